// Round 13
// baseline (364.220 us; speedup 1.0000x reference)
//
#include <hip/hip_runtime.h>
#include <hip/hip_bf16.h>
#include <stdint.h>

// Problem constants (from reference)
#define N_NODES 30000
#define E_EDGES 240000
#define NGRAPH  16
#define D1      256
#define D2      512
#define D3      1024
#define DOUT    1024
#define M_PAD   30720   // 240 * 128: row-panel count divisible by 8 XCDs
#define NT_M    240
#define CAP     40      // max in-degree (Poisson(8): P(>=40) negligible)
#define LSTR    72      // LDS row stride (elems): 144B = 16B-aligned, <=2-way banks

typedef unsigned short ushort_t;
typedef short short8 __attribute__((ext_vector_type(8)));
typedef float f32x4 __attribute__((ext_vector_type(4)));

__device__ __forceinline__ float bf2f(ushort_t u) {
    union { unsigned int i; float f; } v; v.i = ((unsigned int)u) << 16; return v.f;
}
__device__ __forceinline__ ushort_t f2bf(float x) {
    union { float f; unsigned int i; } v; v.f = x;
    unsigned int r = v.i + 0x7fffu + ((v.i >> 16) & 1u);   // RNE
    return (ushort_t)(r >> 16);
}

// ---------------- runtime dtype detection (parallel: 64 lanes, 1 load each) ----------------
__global__ void k_detect(const void* w1, const void* ei, int* flags) {
    int lane = threadIdx.x & 63;
    const ushort_t* h = (const ushort_t*)w1;
    float v = fabsf(bf2f(h[lane * 2]));
    unsigned long long badf = __ballot(!(v <= 0.25f));      // NaN also trips
    const int* e = (const int*)ei;
    unsigned long long badi = __ballot(e[lane * 2 + 1] != 0);
    if (threadIdx.x == 0) {
        flags[0] = (badf == 0ull) ? 1 : 0;
        flags[1] = (badi == 0ull) ? 1 : 0;
    }
}

// ---------------- fused setup: conversions + inits + weight transposes ----------------
__global__ void k_setup(const void* x, const void* batch, const void* w1, const void* b1,
                        const void* b2, const void* b3, const void* bo,
                        const void* W2, const void* W3,
                        float* xf, int* batch32, float* W1f, float* b1f, float* b2f,
                        float* b3f, float* bof, ushort_t* Wt2, ushort_t* Wt3,
                        int* slotcnt, float* pooled, float* pooled2, const int* flags) {
    int isbf = flags[0];
    int bid = blockIdx.x;
    int tid = threadIdx.x;
    if (bid < 492) {
        int i = bid * 256 + tid;
        if (i < 3072) {                              // small arrays
            const void* src; float* dst; int idx;
            if      (i < 256)  { src = w1; dst = W1f; idx = i; }
            else if (i < 512)  { src = b1; dst = b1f; idx = i - 256; }
            else if (i < 1024) { src = b2; dst = b2f; idx = i - 512; }
            else if (i < 2048) { src = b3; dst = b3f; idx = i - 1024; }
            else               { src = bo; dst = bof; idx = i - 2048; }
            dst[idx] = isbf ? bf2f(((const ushort_t*)src)[idx]) : ((const float*)src)[idx];
        } else if (i < 33072) {                      // x
            int idx = i - 3072;
            xf[idx] = isbf ? bf2f(((const ushort_t*)x)[idx]) : ((const float*)x)[idx];
        } else if (i < 63072) {                      // batch
            int idx = i - 33072;
            batch32[idx] = flags[1] ? (int)((const long long*)batch)[idx]
                                    : ((const int*)batch)[idx];
        } else if (i < 93072) {                      // slotcnt init
            slotcnt[i - 63072] = 0;
        } else if (i < 109456) {                     // pooled init
            pooled[i - 93072] = 0.0f;
        } else if (i < 125840) {                     // pooled2 init
            pooled2[i - 109456] = 0.0f;
        }
    } else {                                         // transpose-cvt tiles (32x32)
        __shared__ ushort_t tile[32][33];
        int tb = bid - 492;
        const void* in; ushort_t* out; int R, C, bx, by;
        if (tb < 128) { in = W2; out = Wt2; R = D1; C = D2; bx = tb & 15; by = tb >> 4; }
        else { tb -= 128; in = W3; out = Wt3; R = D2; C = D3; bx = tb & 31; by = tb >> 5; }
        int tx = tid & 31, ty = tid >> 5;
        int c0 = bx * 32, r0 = by * 32;
        for (int i = ty; i < 32; i += 8) {
            size_t idx = (size_t)(r0 + i) * C + c0 + tx;
            tile[i][tx] = isbf ? ((const ushort_t*)in)[idx] : f2bf(((const float*)in)[idx]);
        }
        __syncthreads();
        for (int i = ty; i < 32; i += 8) out[(size_t)(c0 + i) * R + r0 + tx] = tile[tx][i];
    }
}

// ---------------- adjacency build (reads raw edge_index) ----------------
__global__ void k_edge_count(const void* ei, int* slotcnt, int* slots, const int* flags) {
    int e = blockIdx.x * 256 + threadIdx.x;
    if (e >= E_EDGES) return;
    int s, d;
    if (flags[1]) {
        s = (int)((const long long*)ei)[e];
        d = (int)((const long long*)ei)[E_EDGES + e];
    } else {
        s = ((const int*)ei)[e];
        d = ((const int*)ei)[E_EDGES + e];
    }
    if ((unsigned)s >= N_NODES || (unsigned)d >= N_NODES) return;
    int pos = atomicAdd(&slotcnt[d], 1);
    if (pos < CAP) slots[d * CAP + pos] = s;
}

// dis = rsqrt(1+indeg); block 118 computes per-graph counts via binary search
__global__ void k_node_cnt(const int* slotcnt, float* dis, const int* batch, float* cntg) {
    int b = blockIdx.x;
    if (b < 118) {
        int i = b * 256 + threadIdx.x;
        if (i < N_NODES) dis[i] = rsqrtf(1.0f + (float)slotcnt[i]);
    } else {
        int g = threadIdx.x;
        if (g >= NGRAPH) return;
        int lo0 = 0, hi0 = N_NODES;
        while (lo0 < hi0) { int m = (lo0 + hi0) >> 1; if (batch[m] < g) lo0 = m + 1; else hi0 = m; }
        int lo1 = lo0, hi1 = N_NODES;
        while (lo1 < hi1) { int m = (lo1 + hi1) >> 1; if (batch[m] < g + 1) lo1 = m + 1; else hi1 = m; }
        cntg[g] = (float)(lo1 - lo0);
    }
}

// s1[d] = x[d]*dis[d]^2 + dis[d]*sum_s x[s]*dis[s]
__global__ void k_s1(const float* xf, const float* dis, const int* slots,
                     const int* slotcnt, float* s1) {
    int d = blockIdx.x * 256 + threadIdx.x;
    if (d >= N_NODES) return;
    float di = dis[d];
    int cnt = slotcnt[d]; cnt = cnt < CAP ? cnt : CAP;
    float acc = xf[d] * di;
    for (int k = 0; k < cnt; k++) {
        int s = slots[d * CAP + k];
        acc += xf[s] * dis[s];
    }
    s1[d] = acc * di;
}

// ---------------- fused layer-1 + layer-2 aggregation: wave per node, 4 ch/lane ----------------
__global__ void k_agg1(const float* s1, const float* W1f, const float* b1f,
                       ushort_t* a2, const int* slots, const int* slotcnt, const float* dis) {
    int node = blockIdx.x * 4 + (threadIdx.x >> 6);
    int lane = threadIdx.x & 63;
    int c4 = lane * 4;
    float w[4], bb[4], a[4];
    #pragma unroll
    for (int j = 0; j < 4; j++) { w[j] = W1f[c4 + j]; bb[j] = b1f[c4 + j]; }
    float di = dis[node];
    int cnt = slotcnt[node]; cnt = cnt < CAP ? cnt : CAP;
    float sv = s1[node];
    float wsl = di * di;
    #pragma unroll
    for (int j = 0; j < 4; j++) a[j] = wsl * fmaxf(sv * w[j] + bb[j], 0.0f);
    for (int k = 0; k < cnt; k++) {
        int s = slots[node * CAP + k];
        float ss = s1[s];
        float wn = dis[s] * di;
        #pragma unroll
        for (int j = 0; j < 4; j++) a[j] += wn * fmaxf(ss * w[j] + bb[j], 0.0f);
    }
    uint2 o;
    o.x = (unsigned int)f2bf(a[0]) | ((unsigned int)f2bf(a[1]) << 16);
    o.y = (unsigned int)f2bf(a[2]) | ((unsigned int)f2bf(a[3]) << 16);
    *(uint2*)&a2[(size_t)node * D1 + c4] = o;
}

// ---------------- layer-3 aggregation: wave/node, 8 ch/lane, 2-deep gather pipeline ----------------
__global__ void k_agg2(const ushort_t* h, ushort_t* out, const int* slots,
                       const int* slotcnt, const float* dis) {
    int node = blockIdx.x * 4 + (threadIdx.x >> 6);
    int lane = threadIdx.x & 63;
    int c8 = lane * 8;
    float di = dis[node];
    int cnt = slotcnt[node]; cnt = cnt < CAP ? cnt : CAP;
    float w = di * di;
    const ushort_t* hp = h + c8;
    short8 p = *(const short8*)&hp[(size_t)node * D2];
    float a[8];
    #pragma unroll
    for (int j = 0; j < 8; j++) a[j] = w * bf2f((ushort_t)p[j]);
    if (cnt > 0) {
        int s0 = slots[node * CAP];
        short8 q0 = *(const short8*)&hp[(size_t)s0 * D2];
        float ws0 = dis[s0] * di;
        for (int k = 1; k < cnt; k++) {
            int s1i = slots[node * CAP + k];          // next load in flight
            short8 q1 = *(const short8*)&hp[(size_t)s1i * D2];
            float ws1 = dis[s1i] * di;
            #pragma unroll
            for (int j = 0; j < 8; j++) a[j] += ws0 * bf2f((ushort_t)q0[j]);
            q0 = q1; ws0 = ws1;
        }
        #pragma unroll
        for (int j = 0; j < 8; j++) a[j] += ws0 * bf2f((ushort_t)q0[j]);
    }
    uint4 o;
    o.x = (unsigned int)f2bf(a[0]) | ((unsigned int)f2bf(a[1]) << 16);
    o.y = (unsigned int)f2bf(a[2]) | ((unsigned int)f2bf(a[3]) << 16);
    o.z = (unsigned int)f2bf(a[4]) | ((unsigned int)f2bf(a[5]) << 16);
    o.w = (unsigned int)f2bf(a[6]) | ((unsigned int)f2bf(a[7]) << 16);
    *(uint4*)&out[(size_t)node * D2 + c8] = o;
}

// ---------------- BK=64 pipelined MFMA bf16 GEMM, 128x128 tile ----------------
// r12 fix: double the MFMA-per-barrier density at CONSTANT occupancy.
// 32 MFMA/iter/wave (2 k-halves of 16), 8 iters at K=512. acc stays 4x4 (64 AGPR,
// the r7 killer was 4x8 = 128 AGPR -> 1 wave/SIMD). LDS 72KB (2 blocks/CU),
// stride-72 rows: 144B = 16B-aligned, <=2-way bank alias (free, m136).
__global__ __launch_bounds__(256, 2) void k_gemm(const ushort_t* A, const ushort_t* Bt,
                                                 const float* bias, ushort_t* Cmat,
                                                 int K, int Ncols, int ntn) {
    __shared__ __align__(16) ushort_t As[2][128 * LSTR];
    __shared__ __align__(16) ushort_t Bs[2][128 * LSTR];
    int tid = threadIdx.x;
    int id = blockIdx.x;
    int xcd = id & 7, q = id >> 3;
    int rt = xcd * (NT_M / 8) + q / ntn;
    int ct = q % ntn;
    int bm0 = rt * 128, bn0 = ct * 128;
    int wave = tid >> 6, lane = tid & 63;
    int wm = (wave & 1) * 64, wn = (wave >> 1) * 64;
    int l15 = lane & 15, quad = lane >> 4;

    // staging: thread t -> row t>>1, 32 contiguous elems at (t&1)*32 (4 uint4 each mat)
    int srow = tid >> 1, skofs = (tid & 1) * 32;
    int sofs = srow * LSTR + skofs;
    const ushort_t* gA = A + (size_t)(bm0 + srow) * K + skofs;
    const ushort_t* gB = Bt + (size_t)(bn0 + srow) * K + skofs;

    {   // prologue: tile 0 -> buf 0
        #pragma unroll
        for (int j = 0; j < 4; j++) {
            uint4 a = *(const uint4*)(gA + j * 8);
            uint4 b = *(const uint4*)(gB + j * 8);
            *(uint4*)&As[0][sofs + j * 8] = a;
            *(uint4*)&Bs[0][sofs + j * 8] = b;
        }
    }

    f32x4 acc[4][4];
    for (int a = 0; a < 4; a++)
        for (int b = 0; b < 4; b++)
            acc[a][b] = (f32x4){0.f, 0.f, 0.f, 0.f};

    int niter = K >> 6;
    for (int it = 0; it < niter; ++it) {
        __syncthreads();
        int kb = (it + 1) << 6;
        uint4 na[4], nb[4];
        if (kb < K) {
            #pragma unroll
            for (int j = 0; j < 4; j++) {
                na[j] = *(const uint4*)(gA + kb + j * 8);
                nb[j] = *(const uint4*)(gB + kb + j * 8);
            }
        }
        int cb = it & 1;
        #pragma unroll
        for (int h = 0; h < 2; h++) {
            short8 af[4], bfr[4];
            #pragma unroll
            for (int im = 0; im < 4; im++)
                af[im] = *(const short8*)&As[cb][(wm + im * 16 + l15) * LSTR + h * 32 + quad * 8];
            #pragma unroll
            for (int in = 0; in < 4; in++)
                bfr[in] = *(const short8*)&Bs[cb][(wn + in * 16 + l15) * LSTR + h * 32 + quad * 8];
            #pragma unroll
            for (int im = 0; im < 4; im++)
                #pragma unroll
                for (int in = 0; in < 4; in++)
                    acc[im][in] = __builtin_amdgcn_mfma_f32_16x16x32_bf16(af[im], bfr[in], acc[im][in], 0, 0, 0);
        }
        if (kb < K) {
            int wb = cb ^ 1;
            #pragma unroll
            for (int j = 0; j < 4; j++) {
                *(uint4*)&As[wb][sofs + j * 8] = na[j];
                *(uint4*)&Bs[wb][sofs + j * 8] = nb[j];
            }
        }
    }

    // epilogue: C/D layout col=lane&15, row=quad*4+r  [m89-verified]
    for (int im = 0; im < 4; im++) {
        int row = bm0 + wm + im * 16 + quad * 4;
        for (int in = 0; in < 4; in++) {
            int col = bn0 + wn + in * 16 + l15;
            float bv = bias[col];
            for (int r = 0; r < 4; r++) {
                float v = acc[im][in][r] + bv;
                v = v > 0.0f ? v : 0.0f;
                Cmat[(size_t)(row + r) * Ncols + col] = f2bf(v);
            }
        }
    }
}

// ---------------- BK=64 GEMM + fused mean-pool (pool table aliased onto dead LDS) ----------------
__global__ __launch_bounds__(256, 2) void k_gemm_pool(const ushort_t* A, const ushort_t* Bt,
                                                      const float* bias, const int* batch,
                                                      float* pooled, int K, int ntn) {
    __shared__ __align__(16) ushort_t As[2][128 * LSTR];
    __shared__ __align__(16) ushort_t Bs[2][128 * LSTR];
    int tid = threadIdx.x;
    int id = blockIdx.x;
    int xcd = id & 7, q = id >> 3;
    int rt = xcd * (NT_M / 8) + q / ntn;
    int ct = q % ntn;
    int bm0 = rt * 128, bn0 = ct * 128;
    int wave = tid >> 6, lane = tid & 63;
    int wm = (wave & 1) * 64, wn = (wave >> 1) * 64;
    int l15 = lane & 15, quad = lane >> 4;

    int srow = tid >> 1, skofs = (tid & 1) * 32;
    int sofs = srow * LSTR + skofs;
    const ushort_t* gA = A + (size_t)(bm0 + srow) * K + skofs;
    const ushort_t* gB = Bt + (size_t)(bn0 + srow) * K + skofs;

    {
        #pragma unroll
        for (int j = 0; j < 4; j++) {
            uint4 a = *(const uint4*)(gA + j * 8);
            uint4 b = *(const uint4*)(gB + j * 8);
            *(uint4*)&As[0][sofs + j * 8] = a;
            *(uint4*)&Bs[0][sofs + j * 8] = b;
        }
    }

    f32x4 acc[4][4];
    for (int a = 0; a < 4; a++)
        for (int b = 0; b < 4; b++)
            acc[a][b] = (f32x4){0.f, 0.f, 0.f, 0.f};

    int niter = K >> 6;
    for (int it = 0; it < niter; ++it) {
        __syncthreads();
        int kb = (it + 1) << 6;
        uint4 na[4], nb[4];
        if (kb < K) {
            #pragma unroll
            for (int j = 0; j < 4; j++) {
                na[j] = *(const uint4*)(gA + kb + j * 8);
                nb[j] = *(const uint4*)(gB + kb + j * 8);
            }
        }
        int cb = it & 1;
        #pragma unroll
        for (int h = 0; h < 2; h++) {
            short8 af[4], bfr[4];
            #pragma unroll
            for (int im = 0; im < 4; im++)
                af[im] = *(const short8*)&As[cb][(wm + im * 16 + l15) * LSTR + h * 32 + quad * 8];
            #pragma unroll
            for (int in = 0; in < 4; in++)
                bfr[in] = *(const short8*)&Bs[cb][(wn + in * 16 + l15) * LSTR + h * 32 + quad * 8];
            #pragma unroll
            for (int im = 0; im < 4; im++)
                #pragma unroll
                for (int in = 0; in < 4; in++)
                    acc[im][in] = __builtin_amdgcn_mfma_f32_16x16x32_bf16(af[im], bfr[in], acc[im][in], 0, 0, 0);
        }
        if (kb < K) {
            int wb = cb ^ 1;
            #pragma unroll
            for (int j = 0; j < 4; j++) {
                *(uint4*)&As[wb][sofs + j * 8] = na[j];
                *(uint4*)&Bs[wb][sofs + j * 8] = nb[j];
            }
        }
    }

    // ---- pool epilogue: As/Bs are dead -> alias pool table into them ----
    __syncthreads();
    float* pl = (float*)&As[0][0];            // NGRAPH*128 floats = 8KB
    int* gtile = (int*)&Bs[0][0];             // 128 ints
    for (int i = tid; i < NGRAPH * 128; i += 256) pl[i] = 0.0f;
    if (tid < 128) {
        int r = bm0 + tid; if (r > N_NODES - 1) r = N_NODES - 1;
        int g = batch[r]; g = g < 0 ? 0 : (g > NGRAPH - 1 ? NGRAPH - 1 : g);
        gtile[tid] = g;
    }
    __syncthreads();

    int gmin = gtile[0], gmax = gtile[127];
    if (gmin == gmax && bm0 + 127 < N_NODES) {
        // FAST PATH (~95% of tiles): uniform graph id, no padding rows.
        float csum[4];
        #pragma unroll
        for (int in = 0; in < 4; in++) csum[in] = 0.0f;
        for (int im = 0; im < 4; im++) {
            #pragma unroll
            for (int in = 0; in < 4; in++) {
                float bv = bias[bn0 + wn + in * 16 + l15];
                #pragma unroll
                for (int r = 0; r < 4; r++)
                    csum[in] += fmaxf(acc[im][in][r] + bv, 0.0f);
            }
        }
        #pragma unroll
        for (int in = 0; in < 4; in++) {
            csum[in] += __shfl_xor(csum[in], 16);
            csum[in] += __shfl_xor(csum[in], 32);
        }
        if (quad == 0) {
            #pragma unroll
            for (int in = 0; in < 4; in++)
                atomicAdd(&pl[gmin * 128 + wn + in * 16 + l15], csum[in]);
        }
    } else {
        // slow path: per-row graph segmentation
        for (int im = 0; im < 4; im++) {
            int rl = wm + im * 16 + quad * 4;
            for (int in = 0; in < 4; in++) {
                int cl = wn + in * 16 + l15;
                float bv = bias[bn0 + cl];
                float vsum = 0.0f;
                int gprev = gtile[rl];
                for (int r = 0; r < 4; r++) {
                    int row = bm0 + rl + r;
                    float v = (row < N_NODES) ? fmaxf(acc[im][in][r] + bv, 0.0f) : 0.0f;
                    int g = gtile[rl + r];
                    if (g != gprev) {
                        atomicAdd(&pl[gprev * 128 + cl], vsum);
                        vsum = 0.0f; gprev = g;
                    }
                    vsum += v;
                }
                atomicAdd(&pl[gprev * 128 + cl], vsum);
            }
        }
    }
    __syncthreads();

    int span = (gmax - gmin + 1) * 128;
    for (int idx = tid; idx < span; idx += 256) {
        int g = gmin + (idx >> 7), cl = idx & 127;
        float v = pl[g * 128 + cl];
        if (v != 0.0f) atomicAdd(&pooled[g * DOUT + bn0 + cl], v);
    }
}

// ---------------- output GEMM stage 1 (LDS-staged pooled, k-chunked grid) ----------------
__global__ __launch_bounds__(256) void k_out_partial(const float* pooled, const void* Wo,
                                                     float* pooled2, const int* flags) {
    __shared__ float pl[NGRAPH * 32];
    int tid = threadIdx.x;
    int col = blockIdx.x * 256 + tid;
    int k0 = blockIdx.y * 32;
    for (int i = tid; i < NGRAPH * 32; i += 256) {
        int g = i >> 5, kk = i & 31;
        pl[i] = pooled[g * D3 + k0 + kk];
    }
    __syncthreads();
    int isbf = flags[0];
    float acc[NGRAPH];
    #pragma unroll
    for (int g = 0; g < NGRAPH; g++) acc[g] = 0.0f;
    #pragma unroll 4
    for (int kk = 0; kk < 32; kk++) {
        int k = k0 + kk;
        float wv = isbf ? bf2f(((const ushort_t*)Wo)[(size_t)k * DOUT + col])
                        : ((const float*)Wo)[(size_t)k * DOUT + col];
        #pragma unroll
        for (int g = 0; g < NGRAPH; g++)
            acc[g] += pl[g * 32 + kk] * wv;
    }
    #pragma unroll
    for (int g = 0; g < NGRAPH; g++)
        atomicAdd(&pooled2[g * DOUT + col], acc[g]);
}

__global__ void k_out_fin(const float* pooled2, const float* bof, const float* cntg,
                          void* out, const int* flags) {
    int i = blockIdx.x * 256 + threadIdx.x;
    int g = i >> 10, o = i & 1023;
    float c = cntg[g]; c = c > 1.0f ? c : 1.0f;
    float v = pooled2[i] / c + bof[o];
    if (flags[0]) ((ushort_t*)out)[i] = f2bf(v);
    else          ((float*)out)[i] = v;
}

// ---------------- launch ----------------
extern "C" void kernel_launch(void* const* d_in, const int* in_sizes, int n_in,
                              void* d_out, int out_size, void* d_ws, size_t ws_size,
                              hipStream_t stream) {
    const void* x_raw  = d_in[0];
    const void* ei_raw = d_in[1];
    const void* b_raw  = d_in[2];
    const void* W1_raw = d_in[3];
    const void* b1_raw = d_in[4];
    const void* W2_raw = d_in[5];
    const void* b2_raw = d_in[6];
    const void* W3_raw = d_in[7];
    const void* b3_raw = d_in[8];
    const void* Wo_raw = d_in[9];
    const void* bo_raw = d_in[10];

    char* w = (char*)d_ws;
    size_t off = 0;
    auto alloc = [&](size_t b) { size_t o = off; off += (b + 255) & ~(size_t)255; return o; };
    int*   flags   = (int*)  (w + alloc(256));
    float* xf      = (float*)(w + alloc((size_t)N_NODES * 4));
    int*   batch32 = (int*)  (w + alloc((size_t)N_NODES * 4));
    float* W1f     = (float*)(w + alloc(D1 * 4));
    float* b1f     = (float*)(w + alloc(D1 * 4));
    float* b2f     = (float*)(w + alloc(D2 * 4));
    float* b3f     = (float*)(w + alloc(D3 * 4));
    float* bof     = (float*)(w + alloc(DOUT * 4));
    float* dis     = (float*)(w + alloc((size_t)N_NODES * 4));
    float* s1      = (float*)(w + alloc((size_t)N_NODES * 4));
    float* cntg    = (float*)(w + alloc(64));
    float* pooled  = (float*)(w + alloc((size_t)NGRAPH * DOUT * 4));
    float* pooled2 = (float*)(w + alloc((size_t)NGRAPH * DOUT * 4));
    int*   slotcnt = (int*)  (w + alloc((size_t)N_NODES * 4));
    int*   slots   = (int*)  (w + alloc((size_t)N_NODES * CAP * 4));
    ushort_t* Wt2  = (ushort_t*)(w + alloc((size_t)D2 * D1 * 2));
    ushort_t* Wt3  = (ushort_t*)(w + alloc((size_t)D3 * D2 * 2));
    ushort_t* slabA = (ushort_t*)(w + alloc((size_t)M_PAD * D2 * 2));
    ushort_t* a2 = slabA;       // M_PAD x 256, dies after k_gemm
    ushort_t* a3 = slabA;       // M_PAD x 512, reuses slab
    ushort_t* h2   = (ushort_t*)(w + alloc((size_t)M_PAD * D2 * 2));

    int nb_e = (E_EDGES + 255) / 256;

    k_detect<<<1, 64, 0, stream>>>(W1_raw, ei_raw, flags);
    k_setup<<<1132, 256, 0, stream>>>(x_raw, b_raw, W1_raw, b1_raw, b2_raw, b3_raw, bo_raw,
                                      W2_raw, W3_raw, xf, batch32, W1f, b1f, b2f, b3f, bof,
                                      Wt2, Wt3, slotcnt, pooled, pooled2, flags);
    k_edge_count<<<nb_e, 256, 0, stream>>>(ei_raw, slotcnt, slots, flags);
    k_node_cnt<<<119, 256, 0, stream>>>(slotcnt, dis, batch32, cntg);
    k_s1<<<118, 256, 0, stream>>>(xf, dis, slots, slotcnt, s1);

    k_agg1<<<N_NODES / 4, 256, 0, stream>>>(s1, W1f, b1f, a2, slots, slotcnt, dis);
    k_gemm<<<NT_M * (D2 / 128), 256, 0, stream>>>(a2, Wt2, b2f, h2, D1, D2, D2 / 128);
    k_agg2<<<N_NODES / 4, 256, 0, stream>>>(h2, a3, slots, slotcnt, dis);
    k_gemm_pool<<<NT_M * (D3 / 128), 256, 0, stream>>>(a3, Wt3, b3f, batch32, pooled, D2, D3 / 128);

    k_out_partial<<<dim3(DOUT / 256, D3 / 32), 256, 0, stream>>>(pooled, Wo_raw, pooled2, flags);
    k_out_fin<<<NGRAPH * DOUT / 256, 256, 0, stream>>>(pooled2, bof, cntg, d_out, flags);
}

// Round 15
// 245.042 us; speedup vs baseline: 1.4864x; 1.4864x over previous
//
#include <hip/hip_runtime.h>
#include <hip/hip_bf16.h>
#include <stdint.h>

// Problem constants (from reference)
#define N_NODES 30000
#define E_EDGES 240000
#define NGRAPH  16
#define D1      256
#define D2      512
#define D3      1024
#define DOUT    1024
#define M_PAD   30720   // 240 * 128: row-panel count divisible by 8 XCDs
#define NT_M    240
#define CAP     40      // max in-degree (Poisson(8): P(>=40) negligible)

typedef unsigned short ushort_t;
typedef short short8 __attribute__((ext_vector_type(8)));
typedef float f32x4 __attribute__((ext_vector_type(4)));

__device__ __forceinline__ float bf2f(ushort_t u) {
    union { unsigned int i; float f; } v; v.i = ((unsigned int)u) << 16; return v.f;
}
__device__ __forceinline__ ushort_t f2bf(float x) {
    union { float f; unsigned int i; } v; v.f = x;
    unsigned int r = v.i + 0x7fffu + ((v.i >> 16) & 1u);   // RNE
    return (ushort_t)(r >> 16);
}

// ---------------- runtime dtype detection (parallel: 64 lanes, 1 load each) ----------------
__global__ void k_detect(const void* w1, const void* ei, int* flags) {
    int lane = threadIdx.x & 63;
    const ushort_t* h = (const ushort_t*)w1;
    float v = fabsf(bf2f(h[lane * 2]));
    unsigned long long badf = __ballot(!(v <= 0.25f));      // NaN also trips
    const int* e = (const int*)ei;
    unsigned long long badi = __ballot(e[lane * 2 + 1] != 0);
    if (threadIdx.x == 0) {
        flags[0] = (badf == 0ull) ? 1 : 0;
        flags[1] = (badi == 0ull) ? 1 : 0;
    }
}

// ---------------- fused setup: conversions + inits + weight transposes ----------------
__global__ void k_setup(const void* x, const void* batch, const void* w1, const void* b1,
                        const void* b2, const void* b3, const void* bo,
                        const void* W2, const void* W3,
                        float* xf, int* batch32, float* W1f, float* b1f, float* b2f,
                        float* b3f, float* bof, ushort_t* Wt2, ushort_t* Wt3,
                        int* slotcnt, float* pooled, float* pooled2, const int* flags) {
    int isbf = flags[0];
    int bid = blockIdx.x;
    int tid = threadIdx.x;
    if (bid < 492) {
        int i = bid * 256 + tid;
        if (i < 3072) {                              // small arrays
            const void* src; float* dst; int idx;
            if      (i < 256)  { src = w1; dst = W1f; idx = i; }
            else if (i < 512)  { src = b1; dst = b1f; idx = i - 256; }
            else if (i < 1024) { src = b2; dst = b2f; idx = i - 512; }
            else if (i < 2048) { src = b3; dst = b3f; idx = i - 1024; }
            else               { src = bo; dst = bof; idx = i - 2048; }
            dst[idx] = isbf ? bf2f(((const ushort_t*)src)[idx]) : ((const float*)src)[idx];
        } else if (i < 33072) {                      // x
            int idx = i - 3072;
            xf[idx] = isbf ? bf2f(((const ushort_t*)x)[idx]) : ((const float*)x)[idx];
        } else if (i < 63072) {                      // batch
            int idx = i - 33072;
            batch32[idx] = flags[1] ? (int)((const long long*)batch)[idx]
                                    : ((const int*)batch)[idx];
        } else if (i < 93072) {                      // slotcnt init
            slotcnt[i - 63072] = 0;
        } else if (i < 109456) {                     // pooled init
            pooled[i - 93072] = 0.0f;
        } else if (i < 125840) {                     // pooled2 init
            pooled2[i - 109456] = 0.0f;
        }
    } else {                                         // transpose-cvt tiles (32x32)
        __shared__ ushort_t tile[32][33];
        int tb = bid - 492;
        const void* in; ushort_t* out; int R, C, bx, by;
        if (tb < 128) { in = W2; out = Wt2; R = D1; C = D2; bx = tb & 15; by = tb >> 4; }
        else { tb -= 128; in = W3; out = Wt3; R = D2; C = D3; bx = tb & 31; by = tb >> 5; }
        int tx = tid & 31, ty = tid >> 5;
        int c0 = bx * 32, r0 = by * 32;
        for (int i = ty; i < 32; i += 8) {
            size_t idx = (size_t)(r0 + i) * C + c0 + tx;
            tile[i][tx] = isbf ? ((const ushort_t*)in)[idx] : f2bf(((const float*)in)[idx]);
        }
        __syncthreads();
        for (int i = ty; i < 32; i += 8) out[(size_t)(c0 + i) * R + r0 + tx] = tile[tx][i];
    }
}

// ---------------- adjacency build (reads raw edge_index) ----------------
__global__ void k_edge_count(const void* ei, int* slotcnt, int* slots, const int* flags) {
    int e = blockIdx.x * 256 + threadIdx.x;
    if (e >= E_EDGES) return;
    int s, d;
    if (flags[1]) {
        s = (int)((const long long*)ei)[e];
        d = (int)((const long long*)ei)[E_EDGES + e];
    } else {
        s = ((const int*)ei)[e];
        d = ((const int*)ei)[E_EDGES + e];
    }
    if ((unsigned)s >= N_NODES || (unsigned)d >= N_NODES) return;
    int pos = atomicAdd(&slotcnt[d], 1);
    if (pos < CAP) slots[d * CAP + pos] = s;
}

// ---------------- s1 + dis (folded: dis computed inline from slotcnt); block 118 = cnt search ----
__global__ void k_s1(const float* xf, const int* slotcnt, const int* slots,
                     const int* batch, float* dis, float* s1, float* cntg) {
    int b = blockIdx.x;
    if (b == 118) {
        int g = threadIdx.x;
        if (g >= NGRAPH) return;
        int lo0 = 0, hi0 = N_NODES;
        while (lo0 < hi0) { int m = (lo0 + hi0) >> 1; if (batch[m] < g) lo0 = m + 1; else hi0 = m; }
        int lo1 = lo0, hi1 = N_NODES;
        while (lo1 < hi1) { int m = (lo1 + hi1) >> 1; if (batch[m] < g + 1) lo1 = m + 1; else hi1 = m; }
        cntg[g] = (float)(lo1 - lo0);
        return;
    }
    int d = b * 256 + threadIdx.x;
    if (d >= N_NODES) return;
    int cd = slotcnt[d];
    float di = rsqrtf(1.0f + (float)cd);
    dis[d] = di;
    int cnt = cd < CAP ? cd : CAP;
    float acc = xf[d] * di;
    for (int k = 0; k < cnt; k++) {
        int s = slots[d * CAP + k];
        acc += xf[s] * rsqrtf(1.0f + (float)slotcnt[s]);
    }
    s1[d] = acc * di;
}

// ---------------- fused layer-1 + layer-2 aggregation: wave per node, 4 ch/lane ----------------
__global__ void k_agg1(const float* s1, const float* W1f, const float* b1f,
                       ushort_t* a2, const int* slots, const int* slotcnt, const float* dis) {
    int node = blockIdx.x * 4 + (threadIdx.x >> 6);
    int lane = threadIdx.x & 63;
    int c4 = lane * 4;
    float w[4], bb[4], a[4];
    #pragma unroll
    for (int j = 0; j < 4; j++) { w[j] = W1f[c4 + j]; bb[j] = b1f[c4 + j]; }
    float di = dis[node];
    int cnt = slotcnt[node]; cnt = cnt < CAP ? cnt : CAP;
    float sv = s1[node];
    float wsl = di * di;
    #pragma unroll
    for (int j = 0; j < 4; j++) a[j] = wsl * fmaxf(sv * w[j] + bb[j], 0.0f);
    for (int k = 0; k < cnt; k++) {
        int s = slots[node * CAP + k];
        float ss = s1[s];
        float wn = dis[s] * di;
        #pragma unroll
        for (int j = 0; j < 4; j++) a[j] += wn * fmaxf(ss * w[j] + bb[j], 0.0f);
    }
    uint2 o;
    o.x = (unsigned int)f2bf(a[0]) | ((unsigned int)f2bf(a[1]) << 16);
    o.y = (unsigned int)f2bf(a[2]) | ((unsigned int)f2bf(a[3]) << 16);
    *(uint2*)&a2[(size_t)node * D1 + c4] = o;
}

// ---------------- layer-3 aggregation: wave/node, 8 ch/lane, 2-deep gather pipeline ----------------
__global__ void k_agg2(const ushort_t* h, ushort_t* out, const int* slots,
                       const int* slotcnt, const float* dis) {
    int node = blockIdx.x * 4 + (threadIdx.x >> 6);
    int lane = threadIdx.x & 63;
    int c8 = lane * 8;
    float di = dis[node];
    int cnt = slotcnt[node]; cnt = cnt < CAP ? cnt : CAP;
    float w = di * di;
    const ushort_t* hp = h + c8;
    short8 p = *(const short8*)&hp[(size_t)node * D2];
    float a[8];
    #pragma unroll
    for (int j = 0; j < 8; j++) a[j] = w * bf2f((ushort_t)p[j]);
    if (cnt > 0) {
        int s0 = slots[node * CAP];
        short8 q0 = *(const short8*)&hp[(size_t)s0 * D2];
        float ws0 = dis[s0] * di;
        for (int k = 1; k < cnt; k++) {
            int s1i = slots[node * CAP + k];          // next load in flight
            short8 q1 = *(const short8*)&hp[(size_t)s1i * D2];
            float ws1 = dis[s1i] * di;
            #pragma unroll
            for (int j = 0; j < 8; j++) a[j] += ws0 * bf2f((ushort_t)q0[j]);
            q0 = q1; ws0 = ws1;
        }
        #pragma unroll
        for (int j = 0; j < 8; j++) a[j] += ws0 * bf2f((ushort_t)q0[j]);
    }
    uint4 o;
    o.x = (unsigned int)f2bf(a[0]) | ((unsigned int)f2bf(a[1]) << 16);
    o.y = (unsigned int)f2bf(a[2]) | ((unsigned int)f2bf(a[3]) << 16);
    o.z = (unsigned int)f2bf(a[4]) | ((unsigned int)f2bf(a[5]) << 16);
    o.w = (unsigned int)f2bf(a[6]) | ((unsigned int)f2bf(a[7]) << 16);
    *(uint4*)&out[(size_t)node * D2 + c8] = o;
}

// ---------------- pipelined MFMA bf16 GEMM, 128x128, BK=32 (r12-verified structure) ----------------
__global__ __launch_bounds__(256, 3) void k_gemm(const ushort_t* A, const ushort_t* Bt,
                                                 const float* bias, ushort_t* Cmat,
                                                 int K, int Ncols, int ntn) {
    __shared__ __align__(16) ushort_t As[2][128 * 32];
    __shared__ __align__(16) ushort_t Bs[2][128 * 32];
    int tid = threadIdx.x;
    int id = blockIdx.x;
    int xcd = id & 7, q = id >> 3;
    int rt = xcd * (NT_M / 8) + q / ntn;
    int ct = q % ntn;
    int bm0 = rt * 128, bn0 = ct * 128;
    int wave = tid >> 6, lane = tid & 63;
    int wm = (wave & 1) * 64, wn = (wave >> 1) * 64;
    int l15 = lane & 15, quad = lane >> 4;

    int m1 = tid >> 2, k1 = (tid & 3) << 3;
    int m2 = m1 + 64;
    int off1 = m1 * 32 + k1, off2 = m2 * 32 + k1;
    const ushort_t* pA1 = A + (size_t)(bm0 + m1) * K + k1;
    const ushort_t* pA2 = A + (size_t)(bm0 + m2) * K + k1;
    const ushort_t* pB1 = Bt + (size_t)(bn0 + m1) * K + k1;
    const ushort_t* pB2 = Bt + (size_t)(bn0 + m2) * K + k1;

    {   // prologue: tile 0 -> LDS buf0
        uint4 la0 = *(const uint4*)pA1, la1 = *(const uint4*)pA2;
        uint4 lb0 = *(const uint4*)pB1, lb1 = *(const uint4*)pB2;
        *(uint4*)&As[0][off1] = la0; *(uint4*)&As[0][off2] = la1;
        *(uint4*)&Bs[0][off1] = lb0; *(uint4*)&Bs[0][off2] = lb1;
    }

    f32x4 acc[4][4];
    for (int a = 0; a < 4; a++)
        for (int b = 0; b < 4; b++)
            acc[a][b] = (f32x4){0.f, 0.f, 0.f, 0.f};

    int niter = K >> 5;
    for (int it = 0; it < niter; ++it) {
        __syncthreads();
        int ktn = (it + 1) << 5;
        uint4 na0, na1, nb0, nb1;
        if (ktn < K) {
            na0 = *(const uint4*)(pA1 + ktn); na1 = *(const uint4*)(pA2 + ktn);
            nb0 = *(const uint4*)(pB1 + ktn); nb1 = *(const uint4*)(pB2 + ktn);
        }
        int cb = it & 1;
        short8 af[4], bfr[4];
        for (int im = 0; im < 4; im++)
            af[im] = *(const short8*)&As[cb][(wm + im * 16 + l15) * 32 + quad * 8];
        for (int in = 0; in < 4; in++)
            bfr[in] = *(const short8*)&Bs[cb][(wn + in * 16 + l15) * 32 + quad * 8];
        for (int im = 0; im < 4; im++)
            for (int in = 0; in < 4; in++)
                acc[im][in] = __builtin_amdgcn_mfma_f32_16x16x32_bf16(af[im], bfr[in], acc[im][in], 0, 0, 0);
        if (ktn < K) {
            int wb = cb ^ 1;
            *(uint4*)&As[wb][off1] = na0; *(uint4*)&As[wb][off2] = na1;
            *(uint4*)&Bs[wb][off1] = nb0; *(uint4*)&Bs[wb][off2] = nb1;
        }
    }

    // epilogue: C/D layout col=lane&15, row=quad*4+r  [m89-verified]
    for (int im = 0; im < 4; im++) {
        int row = bm0 + wm + im * 16 + quad * 4;
        for (int in = 0; in < 4; in++) {
            int col = bn0 + wn + in * 16 + l15;
            float bv = bias[col];
            for (int r = 0; r < 4; r++) {
                float v = acc[im][in][r] + bv;
                v = v > 0.0f ? v : 0.0f;
                Cmat[(size_t)(row + r) * Ncols + col] = f2bf(v);
            }
        }
    }
}

// ---------------- BK=32 GEMM + fused mean-pool; pool table ALIASED onto dead As/Bs ----------------
// (aliasing correctness-verified r13; keeps LDS at 32.8KB -> 3 blocks/CU at 132 unified regs)
__global__ __launch_bounds__(256, 3) void k_gemm_pool(const ushort_t* A, const ushort_t* Bt,
                                                      const float* bias, const int* batch,
                                                      float* pooled, int K, int ntn) {
    __shared__ __align__(16) ushort_t As[2][128 * 32];
    __shared__ __align__(16) ushort_t Bs[2][128 * 32];
    int tid = threadIdx.x;
    int id = blockIdx.x;
    int xcd = id & 7, q = id >> 3;
    int rt = xcd * (NT_M / 8) + q / ntn;
    int ct = q % ntn;
    int bm0 = rt * 128, bn0 = ct * 128;
    int wave = tid >> 6, lane = tid & 63;
    int wm = (wave & 1) * 64, wn = (wave >> 1) * 64;
    int l15 = lane & 15, quad = lane >> 4;

    int m1 = tid >> 2, k1 = (tid & 3) << 3;
    int m2 = m1 + 64;
    int off1 = m1 * 32 + k1, off2 = m2 * 32 + k1;
    const ushort_t* pA1 = A + (size_t)(bm0 + m1) * K + k1;
    const ushort_t* pA2 = A + (size_t)(bm0 + m2) * K + k1;
    const ushort_t* pB1 = Bt + (size_t)(bn0 + m1) * K + k1;
    const ushort_t* pB2 = Bt + (size_t)(bn0 + m2) * K + k1;

    {
        uint4 la0 = *(const uint4*)pA1, la1 = *(const uint4*)pA2;
        uint4 lb0 = *(const uint4*)pB1, lb1 = *(const uint4*)pB2;
        *(uint4*)&As[0][off1] = la0; *(uint4*)&As[0][off2] = la1;
        *(uint4*)&Bs[0][off1] = lb0; *(uint4*)&Bs[0][off2] = lb1;
    }

    f32x4 acc[4][4];
    for (int a = 0; a < 4; a++)
        for (int b = 0; b < 4; b++)
            acc[a][b] = (f32x4){0.f, 0.f, 0.f, 0.f};

    int niter = K >> 5;
    for (int it = 0; it < niter; ++it) {
        __syncthreads();
        int ktn = (it + 1) << 5;
        uint4 na0, na1, nb0, nb1;
        if (ktn < K) {
            na0 = *(const uint4*)(pA1 + ktn); na1 = *(const uint4*)(pA2 + ktn);
            nb0 = *(const uint4*)(pB1 + ktn); nb1 = *(const uint4*)(pB2 + ktn);
        }
        int cb = it & 1;
        short8 af[4], bfr[4];
        for (int im = 0; im < 4; im++)
            af[im] = *(const short8*)&As[cb][(wm + im * 16 + l15) * 32 + quad * 8];
        for (int in = 0; in < 4; in++)
            bfr[in] = *(const short8*)&Bs[cb][(wn + in * 16 + l15) * 32 + quad * 8];
        for (int im = 0; im < 4; im++)
            for (int in = 0; in < 4; in++)
                acc[im][in] = __builtin_amdgcn_mfma_f32_16x16x32_bf16(af[im], bfr[in], acc[im][in], 0, 0, 0);
        if (ktn < K) {
            int wb = cb ^ 1;
            *(uint4*)&As[wb][off1] = na0; *(uint4*)&As[wb][off2] = na1;
            *(uint4*)&Bs[wb][off1] = nb0; *(uint4*)&Bs[wb][off2] = nb1;
        }
    }

    // ---- pool epilogue: K-loop LDS dead -> alias pool table ----
    __syncthreads();
    float* pl = (float*)&As[0][0];            // NGRAPH*128 floats = 8KB
    int* gtile = (int*)&Bs[0][0];             // 128 ints
    for (int i = tid; i < NGRAPH * 128; i += 256) pl[i] = 0.0f;
    if (tid < 128) {
        int r = bm0 + tid; if (r > N_NODES - 1) r = N_NODES - 1;
        int g = batch[r]; g = g < 0 ? 0 : (g > NGRAPH - 1 ? NGRAPH - 1 : g);
        gtile[tid] = g;
    }
    __syncthreads();

    int gmin = gtile[0], gmax = gtile[127];
    if (gmin == gmax && bm0 + 127 < N_NODES) {
        // FAST PATH (~95% of tiles): uniform graph id, no padding rows.
        float csum[4];
        #pragma unroll
        for (int in = 0; in < 4; in++) csum[in] = 0.0f;
        for (int im = 0; im < 4; im++) {
            #pragma unroll
            for (int in = 0; in < 4; in++) {
                float bv = bias[bn0 + wn + in * 16 + l15];
                #pragma unroll
                for (int r = 0; r < 4; r++)
                    csum[in] += fmaxf(acc[im][in][r] + bv, 0.0f);
            }
        }
        #pragma unroll
        for (int in = 0; in < 4; in++) {
            csum[in] += __shfl_xor(csum[in], 16);
            csum[in] += __shfl_xor(csum[in], 32);
        }
        if (quad == 0) {
            #pragma unroll
            for (int in = 0; in < 4; in++)
                atomicAdd(&pl[gmin * 128 + wn + in * 16 + l15], csum[in]);
        }
    } else {
        // slow path: per-row graph segmentation
        for (int im = 0; im < 4; im++) {
            int rl = wm + im * 16 + quad * 4;
            for (int in = 0; in < 4; in++) {
                int cl = wn + in * 16 + l15;
                float bv = bias[bn0 + cl];
                float vsum = 0.0f;
                int gprev = gtile[rl];
                for (int r = 0; r < 4; r++) {
                    int row = bm0 + rl + r;
                    float v = (row < N_NODES) ? fmaxf(acc[im][in][r] + bv, 0.0f) : 0.0f;
                    int g = gtile[rl + r];
                    if (g != gprev) {
                        atomicAdd(&pl[gprev * 128 + cl], vsum);
                        vsum = 0.0f; gprev = g;
                    }
                    vsum += v;
                }
                atomicAdd(&pl[gprev * 128 + cl], vsum);
            }
        }
    }
    __syncthreads();

    int span = (gmax - gmin + 1) * 128;
    for (int idx = tid; idx < span; idx += 256) {
        int g = gmin + (idx >> 7), cl = idx & 127;
        float v = pl[g * 128 + cl];
        if (v != 0.0f) atomicAdd(&pooled[g * DOUT + bn0 + cl], v);
    }
}

// ---------------- output GEMM stage 1 (LDS-staged pooled, k-chunked grid) ----------------
__global__ __launch_bounds__(256) void k_out_partial(const float* pooled, const void* Wo,
                                                     float* pooled2, const int* flags) {
    __shared__ float pl[NGRAPH * 32];
    int tid = threadIdx.x;
    int col = blockIdx.x * 256 + tid;
    int k0 = blockIdx.y * 32;
    for (int i = tid; i < NGRAPH * 32; i += 256) {
        int g = i >> 5, kk = i & 31;
        pl[i] = pooled[g * D3 + k0 + kk];
    }
    __syncthreads();
    int isbf = flags[0];
    float acc[NGRAPH];
    #pragma unroll
    for (int g = 0; g < NGRAPH; g++) acc[g] = 0.0f;
    #pragma unroll 4
    for (int kk = 0; kk < 32; kk++) {
        int k = k0 + kk;
        float wv = isbf ? bf2f(((const ushort_t*)Wo)[(size_t)k * DOUT + col])
                        : ((const float*)Wo)[(size_t)k * DOUT + col];
        #pragma unroll
        for (int g = 0; g < NGRAPH; g++)
            acc[g] += pl[g * 32 + kk] * wv;
    }
    #pragma unroll
    for (int g = 0; g < NGRAPH; g++)
        atomicAdd(&pooled2[g * DOUT + col], acc[g]);
}

__global__ void k_out_fin(const float* pooled2, const float* bof, const float* cntg,
                          void* out, const int* flags) {
    int i = blockIdx.x * 256 + threadIdx.x;
    int g = i >> 10, o = i & 1023;
    float c = cntg[g]; c = c > 1.0f ? c : 1.0f;
    float v = pooled2[i] / c + bof[o];
    if (flags[0]) ((ushort_t*)out)[i] = f2bf(v);
    else          ((float*)out)[i] = v;
}

// ---------------- launch ----------------
extern "C" void kernel_launch(void* const* d_in, const int* in_sizes, int n_in,
                              void* d_out, int out_size, void* d_ws, size_t ws_size,
                              hipStream_t stream) {
    const void* x_raw  = d_in[0];
    const void* ei_raw = d_in[1];
    const void* b_raw  = d_in[2];
    const void* W1_raw = d_in[3];
    const void* b1_raw = d_in[4];
    const void* W2_raw = d_in[5];
    const void* b2_raw = d_in[6];
    const void* W3_raw = d_in[7];
    const void* b3_raw = d_in[8];
    const void* Wo_raw = d_in[9];
    const void* bo_raw = d_in[10];

    char* w = (char*)d_ws;
    size_t off = 0;
    auto alloc = [&](size_t b) { size_t o = off; off += (b + 255) & ~(size_t)255; return o; };
    int*   flags   = (int*)  (w + alloc(256));
    float* xf      = (float*)(w + alloc((size_t)N_NODES * 4));
    int*   batch32 = (int*)  (w + alloc((size_t)N_NODES * 4));
    float* W1f     = (float*)(w + alloc(D1 * 4));
    float* b1f     = (float*)(w + alloc(D1 * 4));
    float* b2f     = (float*)(w + alloc(D2 * 4));
    float* b3f     = (float*)(w + alloc(D3 * 4));
    float* bof     = (float*)(w + alloc(DOUT * 4));
    float* dis     = (float*)(w + alloc((size_t)N_NODES * 4));
    float* s1      = (float*)(w + alloc((size_t)N_NODES * 4));
    float* cntg    = (float*)(w + alloc(64));
    float* pooled  = (float*)(w + alloc((size_t)NGRAPH * DOUT * 4));
    float* pooled2 = (float*)(w + alloc((size_t)NGRAPH * DOUT * 4));
    int*   slotcnt = (int*)  (w + alloc((size_t)N_NODES * 4));
    int*   slots   = (int*)  (w + alloc((size_t)N_NODES * CAP * 4));
    ushort_t* Wt2  = (ushort_t*)(w + alloc((size_t)D2 * D1 * 2));
    ushort_t* Wt3  = (ushort_t*)(w + alloc((size_t)D3 * D2 * 2));
    ushort_t* slabA = (ushort_t*)(w + alloc((size_t)M_PAD * D2 * 2));
    ushort_t* a2 = slabA;       // M_PAD x 256, dies after k_gemm
    ushort_t* a3 = slabA;       // M_PAD x 512, reuses slab
    ushort_t* h2   = (ushort_t*)(w + alloc((size_t)M_PAD * D2 * 2));

    int nb_e = (E_EDGES + 255) / 256;

    k_detect<<<1, 64, 0, stream>>>(W1_raw, ei_raw, flags);
    k_setup<<<1132, 256, 0, stream>>>(x_raw, b_raw, W1_raw, b1_raw, b2_raw, b3_raw, bo_raw,
                                      W2_raw, W3_raw, xf, batch32, W1f, b1f, b2f, b3f, bof,
                                      Wt2, Wt3, slotcnt, pooled, pooled2, flags);
    k_edge_count<<<nb_e, 256, 0, stream>>>(ei_raw, slotcnt, slots, flags);
    k_s1<<<119, 256, 0, stream>>>(xf, slotcnt, slots, batch32, dis, s1, cntg);

    k_agg1<<<N_NODES / 4, 256, 0, stream>>>(s1, W1f, b1f, a2, slots, slotcnt, dis);
    k_gemm<<<NT_M * (D2 / 128), 256, 0, stream>>>(a2, Wt2, b2f, h2, D1, D2, D2 / 128);
    k_agg2<<<N_NODES / 4, 256, 0, stream>>>(h2, a3, slots, slotcnt, dis);
    k_gemm_pool<<<NT_M * (D3 / 128), 256, 0, stream>>>(a3, Wt3, b3f, batch32, pooled, D2, D3 / 128);

    k_out_partial<<<dim3(DOUT / 256, D3 / 32), 256, 0, stream>>>(pooled, Wo_raw, pooled2, flags);
    k_out_fin<<<NGRAPH * DOUT / 256, 256, 0, stream>>>(pooled2, bof, cntg, d_out, flags);
}